// Round 4
// baseline (6051.892 us; speedup 1.0000x reference)
//
#include <hip/hip_runtime.h>
#include <hip/hip_bf16.h>
#include <math.h>

// Problem constants
#define B_ 8
#define S_ 32
#define J_ 4
#define L_ 32
#define E_ 500
#define H_ 500
#define NI_ 5000
#define NT_ 48
#define G4_ 2000   // 4*H

#define NB_ 25     // blocks per recurrent gang
#define RPB_ 20    // h indices per block (25*20 = 500)
#define TPB_ 640   // threads per recurrent block = 80 cols * 8 batches

__device__ __forceinline__ float sigm(float x) { return 1.f / (1.f + expf(-x)); }
__device__ __forceinline__ float seluf(float x) {
    const float sc = 1.0507009873554805f, al = 1.6732632423543772f;
    return x > 0.f ? sc * x : sc * al * (expf(x) - 1.f);
}
// agent-scope store: write-through to L3 (coherence point), no fence/wbl2
__device__ __forceinline__ void cohstore(float* p, float v) {
    __hip_atomic_store(p, v, __ATOMIC_RELAXED, __HIP_MEMORY_SCOPE_AGENT);
}

// ---------------- zero the flag slots ----------------
__global__ void k_zero(int* p, int n) {
    int i = blockIdx.x * blockDim.x + threadIdx.x;
    if (i < n) __hip_atomic_store(&p[i], 0, __ATOMIC_RELAXED, __HIP_MEMORY_SCOPE_AGENT);
}

// ---------------- embedding gather ----------------
__global__ __launch_bounds__(128) void k_embed(const int* __restrict__ itemv,
                                               const int* __restrict__ histi,
                                               const float* __restrict__ embW,
                                               float* __restrict__ items,
                                               float* __restrict__ histemb) {
    int row = blockIdx.x;
    int id;
    float* dst;
    if (row < 256) { id = itemv[row]; dst = items + (size_t)row * E_; }
    else           { int rr = row - 256; id = histi[rr]; dst = histemb + (size_t)rr * E_; }
    const float4* s = (const float4*)(embW + (size_t)id * E_);
    float4* d = (float4*)dst;
    if (threadIdx.x < 125) d[threadIdx.x] = s[threadIdx.x];
}

// ---------------- generic GEMM: C[M,N] = A[M,K] @ B[N,K]^T + bias[N] ----------------
#define TBM 64
#define TBN 64
#define TBK 16
__global__ __launch_bounds__(256) void k_gemm_bt(const float* __restrict__ A,
                                                 const float* __restrict__ Bm,
                                                 const float* __restrict__ bias,
                                                 float* __restrict__ C,
                                                 int M, int N, int K) {
    __shared__ float As[TBK][TBM + 1];
    __shared__ float Bs[TBK][TBN + 1];
    const int tid = threadIdx.x;
    const int tx = tid & 15, ty = tid >> 4;
    const int row0 = blockIdx.y * TBM, col0 = blockIdx.x * TBN;
    float acc[4][4] = {};
    for (int k0 = 0; k0 < K; k0 += TBK) {
#pragma unroll
        for (int i = 0; i < 4; ++i) {
            int e = tid + i * 256;
            int kk = e & 15, m = e >> 4;
            int gk = k0 + kk;
            float va = 0.f, vb = 0.f;
            int gm = row0 + m, gn = col0 + m;
            if (gk < K) {
                if (gm < M) va = A[(size_t)gm * K + gk];
                if (gn < N) vb = Bm[(size_t)gn * K + gk];
            }
            As[kk][m] = va;
            Bs[kk][m] = vb;
        }
        __syncthreads();
#pragma unroll
        for (int kk = 0; kk < TBK; ++kk) {
            float a[4], bb[4];
#pragma unroll
            for (int i = 0; i < 4; ++i) a[i] = As[kk][ty * 4 + i];
#pragma unroll
            for (int i = 0; i < 4; ++i) bb[i] = Bs[kk][tx * 4 + i];
#pragma unroll
            for (int i = 0; i < 4; ++i)
#pragma unroll
                for (int j = 0; j < 4; ++j) acc[i][j] += a[i] * bb[j];
        }
        __syncthreads();
    }
#pragma unroll
    for (int i = 0; i < 4; ++i) {
        int gm = row0 + ty * 4 + i;
        if (gm >= M) continue;
#pragma unroll
        for (int j = 0; j < 4; ++j) {
            int gn = col0 + tx * 4 + j;
            if (gn < N) C[(size_t)gm * N + gn] = acc[i][j] + (bias ? bias[gn] : 0.f);
        }
    }
}

// ---------------- multi-block batched recurrent kernel (v3) ----------------
// Exchange protocol:
//   producer: gate threads agent-store h (+c) -> write-through to L3;
//             __syncthreads() drains vmcnt per wave (stores complete at L3);
//             tid 0 agent-stores flag[blk] = t+1 (per-block slot, no RMW).
//   consumer: wave 0 polls all NB_ slots (one lane each) until __all >= t;
//             __syncthreads(); then PLAIN CACHED loads of h. Safe because:
//             each h region is written once, first touched by this XCD after
//             the flag, and dispatch-begin invalidated L1/L2 -> the load
//             misses and fills from L3 which has the written-through data.
// No LDS staging: GEMV reads h as float4 global loads inside the FMA loop
// (8 unique lines/wave/k4, L1 reuse across the 10 waves).
__global__ __launch_bounds__(TPB_) void k_rec3(
    const float* __restrict__ xwm, const float* __restrict__ Whm,
    const float* __restrict__ xwd, const float* __restrict__ Whd,
    const int* __restrict__ dilidx,
    const float* __restrict__ xwh, const float* __restrict__ Whh,
    float* __restrict__ outm, float* __restrict__ outh,
    float* __restrict__ csg, float* __restrict__ he,
    int* __restrict__ flags) {
    __shared__ float z_s[80][8];
    __shared__ float c_s[RPB_][8];
    const int tid = threadIdx.x;
    const int gb = blockIdx.x;
    const int role = gb / NB_;          // 0 main, 1 dil, 2 hist
    const int blk = gb - role * NB_;
    const int r0 = blk * RPB_;

    const float* Wh = (role == 0) ? Whm : (role == 1) ? Whd : Whh;
    const float* xw = (role == 0) ? xwm : (role == 1) ? xwd : xwh;
    const int nsteps = (role == 2) ? 128 : 32;
    int* flag = flags + role * 32;      // NB_ slots used

    const int c = tid >> 3;             // 0..79
    const int b = tid & 7;
    const int gate = c / RPB_;          // 0..3 (i,f,g,o)
    const int ri = c - gate * RPB_;     // 0..19
    const int col = gate * 500 + r0 + ri;
    const float4* wp4 = (const float4*)(Wh + (size_t)col * 500);

    if (tid < RPB_ * 8) c_s[tid >> 3][tid & 7] = 0.f;
    // first use of c_s is after the z_s __syncthreads below

    for (int t = 0; t < nsteps; ++t) {
        // xw load is independent of h -> issue before the poll
        float acc = xw[((size_t)(b * nsteps + t)) * G4_ + col];

        if (t > 0) {
            // ---- wait for all blocks of this gang to finish step t-1 ----
            if (tid < 64) {
                while (true) {
                    int v = (tid < NB_)
                        ? __hip_atomic_load(&flag[tid], __ATOMIC_RELAXED,
                                            __HIP_MEMORY_SCOPE_AGENT)
                        : 0x7fffffff;
                    if (__all(v >= t)) break;
                }
            }
            __syncthreads();

            // ---- z += h[t-1] @ Wh^T, h read directly from global (cached) ----
            const float4* hp4;
            if (role == 1) {
                int it = dilidx[b * S_ + t];
                hp4 = (const float4*)(outh + ((size_t)(b * S_ + it)) * H_);
            } else if (role == 0) {
                hp4 = (const float4*)(outm + ((size_t)(b * S_ + (t - 1))) * H_);
            } else {
                hp4 = (const float4*)(he + ((size_t)(b * 128 + (t - 1))) * H_);
            }
            float s0 = 0.f, s1 = 0.f, s2 = 0.f, s3 = 0.f;
#pragma unroll 1
            for (int k4 = 0; k4 < 124; k4 += 4) {
                float4 w0 = wp4[k4],     h0 = hp4[k4];
                float4 w1 = wp4[k4 + 1], h1 = hp4[k4 + 1];
                float4 w2 = wp4[k4 + 2], h2 = hp4[k4 + 2];
                float4 w3 = wp4[k4 + 3], h3 = hp4[k4 + 3];
                s0 += w0.x * h0.x + w0.y * h0.y + w0.z * h0.z + w0.w * h0.w;
                s1 += w1.x * h1.x + w1.y * h1.y + w1.z * h1.z + w1.w * h1.w;
                s2 += w2.x * h2.x + w2.y * h2.y + w2.z * h2.z + w2.w * h2.w;
                s3 += w3.x * h3.x + w3.y * h3.y + w3.z * h3.z + w3.w * h3.w;
            }
            float4 wt = wp4[124], ht = hp4[124];
            s0 += wt.x * ht.x + wt.y * ht.y + wt.z * ht.z + wt.w * ht.w;
            acc += (s0 + s1) + (s2 + s3);
        }
        z_s[c][b] = acc;
        __syncthreads();

        // ---- gate update for this block's 20 h-indices ----
        if (tid < RPB_ * 8) {
            int rr = tid >> 3, bb = tid & 7;
            float zi = z_s[rr][bb];
            float zf = z_s[RPB_ + rr][bb];
            float zg = z_s[2 * RPB_ + rr][bb];
            float zo = z_s[3 * RPB_ + rr][bb];
            int r = r0 + rr;
            float pc;
            if (role == 1) {
                if (t == 0) pc = 0.f;
                else {
                    int it = dilidx[bb * S_ + t];
                    pc = csg[((size_t)(bb * S_ + it)) * H_ + r];  // plain cached: write-once region
                }
            } else {
                pc = c_s[rr][bb];
            }
            float cc = sigm(zf) * pc + sigm(zi) * tanhf(zg);
            float hh = sigm(zo) * tanhf(cc);
            if (role == 0) {
                c_s[rr][bb] = cc;
                cohstore(&outm[((size_t)(bb * S_ + t)) * H_ + r], hh);
            } else if (role == 2) {
                c_s[rr][bb] = cc;
                cohstore(&he[((size_t)(bb * 128 + t)) * H_ + r], hh);
            } else {
                cohstore(&outh[((size_t)(bb * S_ + t)) * H_ + r], hh);
                cohstore(&csg[((size_t)(bb * S_ + t)) * H_ + r], cc);
            }
        }
        __syncthreads();   // drains vmcnt(0): agent-scope stores complete at L3
        if (tid == 0)
            __hip_atomic_store(&flag[blk], t + 1, __ATOMIC_RELAXED,
                               __HIP_MEMORY_SCOPE_AGENT);
    }
}

// ---------------- masked mean pooling ----------------
__global__ __launch_bounds__(512) void k_pool(const float* __restrict__ outm,
                                              const float* __restrict__ mask,
                                              float* __restrict__ pooled) {
    int b = blockIdx.x, tid = threadIdx.x;
    if (tid >= 500) return;
    float acc = 0.f, den = 0.f;
    for (int s = 0; s < S_; ++s) {
        float mk = mask[b * S_ + s];
        acc += outm[((size_t)(b * S_ + s)) * H_ + tid] * mk;
        den += mk;
    }
    pooled[b * H_ + tid] = acc / den;
}

// ---------------- session rep: sess[b,j,s,:] and avgd[b,j,s] ----------------
__global__ __launch_bounds__(512) void k_sess(const int* __restrict__ seqtim,
                                              const int* __restrict__ itemv,
                                              const int* __restrict__ histt,
                                              const int* __restrict__ histi,
                                              const float* __restrict__ timsim,
                                              const float* __restrict__ poid,
                                              const float* __restrict__ he,
                                              float* __restrict__ sess,
                                              float* __restrict__ avgd) {
    int bi = blockIdx.x;                // B*J*31
    int s = bi % 31;
    int tmpv = bi / 31;
    int j = tmpv & 3, b = tmpv >> 2;
    __shared__ float w[L_];
    __shared__ float pd[L_];
    __shared__ float stats[1];
    int tid = threadIdx.x;
    int st = seqtim[b * S_ + s];
    if (tid < L_) {
        int ht = histt[(b * J_ + j) * L_ + tid];
        w[tid] = timsim[st * NT_ + ht];
    }
    if (tid >= 64 && tid < 64 + L_) {   // parallel poi_dist gather
        int l = tid - 64;
        int iv = itemv[b * S_ + s];
        pd[l] = poid[(size_t)iv * NI_ + histi[(b * J_ + j) * L_ + l]];
    }
    __syncthreads();
    if (tid == 64) {
        float a = 0.f;
        for (int l = 0; l < L_; ++l) a += pd[l];
        avgd[(b * J_ + j) * 31 + s] = a * (1.f / 32.f);
    }
    if (tid == 0) {
        float m = -1e30f;
        for (int l = 0; l < L_; ++l) m = fmaxf(m, w[l]);
        float sm = 0.f;
        for (int l = 0; l < L_; ++l) { float e = expf(w[l] - m); w[l] = e; sm += e; }
        stats[0] = 1.f / sm;
    }
    __syncthreads();
    if (tid < 500) {
        float inv = stats[0];
        float acc = 0.f;
        const float* hp = he + ((size_t)(b * J_ * L_ + j * L_)) * H_ + tid;
        for (int l = 0; l < L_; ++l) acc += w[l] * inv * hp[(size_t)l * H_];
        sess[((size_t)((b * J_ + j) * 31 + s)) * H_ + tid] = acc;
    }
}

// ---------------- attention 1 ----------------
__global__ __launch_bounds__(512) void k_att1(const float* __restrict__ sess,
                                              const float* __restrict__ pooled,
                                              float* __restrict__ att1) {
    int bi = blockIdx.x;   // B*31
    int s = bi % 31, b = bi / 31;
    __shared__ float vec[H_];
    __shared__ float part[512];
    int tid = threadIdx.x;
    if (tid < 500) vec[tid] = pooled[b * H_ + tid];
    __syncthreads();
    int j = tid >> 7, i = tid & 127;
    const float* sp = sess + ((size_t)((b * J_ + j) * 31 + s)) * H_;
    float acc = 0.f;
    for (int h = i; h < H_; h += 128) acc += sp[h] * vec[h];
    part[tid] = acc;
    __syncthreads();
    for (int off = 64; off > 0; off >>= 1) {
        if (i < off) part[tid] += part[tid + off];
        __syncthreads();
    }
    float d0 = part[0], d1 = part[128], d2 = part[256], d3 = part[384];
    float m = fmaxf(fmaxf(d0, d1), fmaxf(d2, d3));
    float e0 = expf(d0 - m), e1 = expf(d1 - m), e2 = expf(d2 - m), e3 = expf(d3 - m);
    float inv = 1.f / (e0 + e1 + e2 + e3);
    if (tid < 500) {
        const float* s0 = sess + ((size_t)(b * J_ * 31 + s)) * H_ + tid;
        const size_t js = (size_t)31 * H_;
        float r = e0 * inv * s0[0] + e1 * inv * s0[js] + e2 * inv * s0[2 * js] + e3 * inv * s0[3 * js];
        att1[((size_t)(b * 31 + s)) * H_ + tid] = r;
    }
}

// ---------------- attention 2 ----------------
__global__ __launch_bounds__(512) void k_att2(const float* __restrict__ sess,
                                              const float* __restrict__ outy,
                                              const float* __restrict__ outm,
                                              const float* __restrict__ avgd,
                                              float* __restrict__ X) {
    int bi = blockIdx.x;   // B*31
    int s = bi % 31, b = bi / 31;
    __shared__ float vec[H_];
    __shared__ float part[512];
    int tid = threadIdx.x;
    if (tid < 500)
        vec[tid] = 0.5f * seluf(outy[((size_t)(b * 31 + s)) * H_ + tid]) +
                   0.5f * outm[((size_t)(b * S_ + s)) * H_ + tid];
    __syncthreads();
    int j = tid >> 7, i = tid & 127;
    const float* sp = sess + ((size_t)((b * J_ + j) * 31 + s)) * H_;
    float acc = 0.f;
    for (int h = i; h < H_; h += 128) acc += sp[h] * vec[h];
    part[tid] = acc;
    __syncthreads();
    for (int off = 64; off > 0; off >>= 1) {
        if (i < off) part[tid] += part[tid + off];
        __syncthreads();
    }
    float d0 = part[0]   / avgd[(b * J_ + 0) * 31 + s];
    float d1 = part[128] / avgd[(b * J_ + 1) * 31 + s];
    float d2 = part[256] / avgd[(b * J_ + 2) * 31 + s];
    float d3 = part[384] / avgd[(b * J_ + 3) * 31 + s];
    float m = fmaxf(fmaxf(d0, d1), fmaxf(d2, d3));
    float e0 = expf(d0 - m), e1 = expf(d1 - m), e2 = expf(d2 - m), e3 = expf(d3 - m);
    float inv = 1.f / (e0 + e1 + e2 + e3);
    if (tid < 500) {
        const float* s0 = sess + ((size_t)(b * J_ * 31 + s)) * H_ + tid;
        const size_t js = (size_t)31 * H_;
        float r = e0 * inv * s0[0] + e1 * inv * s0[js] + e2 * inv * s0[2 * js] + e3 * inv * s0[3 * js];
        X[((size_t)(b * S_ + s)) * 1000 + tid] = seluf(r);
    }
}

// ---------------- mix ----------------
__global__ __launch_bounds__(512) void k_mix(const float* __restrict__ outm,
                                             const float* __restrict__ outh,
                                             float* __restrict__ X) {
    int bs = blockIdx.x;   // B*S
    int tid = threadIdx.x;
    if (tid >= 500) return;
    size_t idx = (size_t)bs * H_ + tid;
    float om = 0.5f * (seluf(outm[idx]) + seluf(outh[idx]));
    X[(size_t)bs * 1000 + 500 + tid] = om;
    if ((bs & (S_ - 1)) == S_ - 1) X[(size_t)bs * 1000 + tid] = 0.f;
}

// ---------------- in-place log_softmax over rows of 5000 ----------------
__global__ __launch_bounds__(512) void k_lsm(float* __restrict__ out) {
    int row = blockIdx.x, tid = threadIdx.x;
    float* p = out + (size_t)row * NI_;
    __shared__ float red[512];
    float m = -1e30f;
    for (int i = tid; i < NI_; i += 512) m = fmaxf(m, p[i]);
    red[tid] = m;
    __syncthreads();
    for (int off = 256; off > 0; off >>= 1) {
        if (tid < off) red[tid] = fmaxf(red[tid], red[tid + off]);
        __syncthreads();
    }
    m = red[0];
    __syncthreads();
    float sm = 0.f;
    for (int i = tid; i < NI_; i += 512) sm += expf(p[i] - m);
    red[tid] = sm;
    __syncthreads();
    for (int off = 256; off > 0; off >>= 1) {
        if (tid < off) red[tid] += red[tid + off];
        __syncthreads();
    }
    float lse = m + logf(red[0]);
    __syncthreads();
    for (int i = tid; i < NI_; i += 512) p[i] -= lse;
}

extern "C" void kernel_launch(void* const* d_in, const int* in_sizes, int n_in,
                              void* d_out, int out_size, void* d_ws, size_t ws_size,
                              hipStream_t stream) {
    const int* item_vectors = (const int*)d_in[0];
    const int* sequence_tim = (const int*)d_in[1];
    const int* dilated_idx  = (const int*)d_in[2];
    const int* hist_items   = (const int*)d_in[3];
    const int* hist_tims    = (const int*)d_in[4];
    const float* mask       = (const float*)d_in[5];
    const float* tim_sim    = (const float*)d_in[6];
    const float* poi_dist   = (const float*)d_in[7];
    const float* emb_W      = (const float*)d_in[8];
    const float* lstm_Wi    = (const float*)d_in[9];
    const float* lstm_Wh    = (const float*)d_in[10];
    const float* lstm_b     = (const float*)d_in[11];
    const float* hist_Wi    = (const float*)d_in[12];
    const float* hist_Wh    = (const float*)d_in[13];
    const float* hist_b     = (const float*)d_in[14];
    const float* dil_Wi     = (const float*)d_in[15];
    const float* dil_Wh     = (const float*)d_in[16];
    const float* dil_b      = (const float*)d_in[17];
    const float* lin1_W     = (const float*)d_in[18];
    const float* lin1_b     = (const float*)d_in[19];
    const float* lin_W      = (const float*)d_in[20];
    const float* lin_b      = (const float*)d_in[21];
    float* out = (float*)d_out;
    float* ws  = (float*)d_ws;

    // workspace layout (float offsets)
    float* items   = ws + 0;        // 128000
    float* histemb = ws + 128000;   // 512000
    float* xwm     = ws + 640000;   // 512000
    float* xwd     = ws + 1152000;  // 512000
    float* xwh     = ws + 1664000;  // 2048000
    float* outm    = ws + 3712000;  // 128000
    float* outh    = ws + 3840000;  // 128000
    float* csg     = ws + 3968000;  // 128000
    float* he      = ws + 4096000;  // 512000
    float* pooled  = ws + 4608000;  // 4000
    float* sess    = ws + 4612000;  // 496000
    float* avgd    = ws + 5108000;  // 992
    float* att1    = ws + 5108992;  // 124000
    float* outy    = ws + 5232992;  // 124000
    float* Xbuf    = ws + 5356992;  // 256000
    int*   flags   = (int*)(ws + 5612992);  // 3*32 ints

    k_zero<<<dim3(1), dim3(128), 0, stream>>>(flags, 96);
    k_embed<<<dim3(1280), dim3(128), 0, stream>>>(item_vectors, hist_items, emb_W, items, histemb);

    // input-side GEMMs with bias folded in
    k_gemm_bt<<<dim3(32, 4), dim3(256), 0, stream>>>(items, lstm_Wi, lstm_b, xwm, 256, G4_, E_);
    k_gemm_bt<<<dim3(32, 4), dim3(256), 0, stream>>>(items, dil_Wi, dil_b, xwd, 256, G4_, E_);
    k_gemm_bt<<<dim3(32, 16), dim3(256), 0, stream>>>(histemb, hist_Wi, hist_b, xwh, 1024, G4_, E_);

    k_rec3<<<dim3(3 * NB_), dim3(TPB_), 0, stream>>>(
        xwm, lstm_Wh, xwd, dil_Wh, dilated_idx, xwh, hist_Wh,
        outm, outh, csg, he, flags);

    k_pool<<<dim3(B_), dim3(512), 0, stream>>>(outm, mask, pooled);
    k_sess<<<dim3(B_ * J_ * 31), dim3(512), 0, stream>>>(sequence_tim, item_vectors, hist_tims,
                                                         hist_items, tim_sim, poi_dist, he, sess, avgd);
    k_att1<<<dim3(B_ * 31), dim3(512), 0, stream>>>(sess, pooled, att1);
    k_gemm_bt<<<dim3(8, 4), dim3(256), 0, stream>>>(att1, lin1_W, lin1_b, outy, 248, H_, H_);
    k_att2<<<dim3(B_ * 31), dim3(512), 0, stream>>>(sess, outy, outm, avgd, Xbuf);
    k_mix<<<dim3(B_ * S_), dim3(512), 0, stream>>>(outm, outh, Xbuf);

    k_gemm_bt<<<dim3(79, 4), dim3(256), 0, stream>>>(Xbuf, lin_W, lin_b, out, 256, NI_, 1000);
    k_lsm<<<dim3(256), dim3(512), 0, stream>>>(out);
}

// Round 5
// 1894.062 us; speedup vs baseline: 3.1952x; 3.1952x over previous
//
#include <hip/hip_runtime.h>
#include <hip/hip_bf16.h>
#include <math.h>

// Problem constants
#define B_ 8
#define S_ 32
#define J_ 4
#define L_ 32
#define E_ 500
#define H_ 500
#define NI_ 5000
#define NT_ 48
#define G4_ 2000   // 4*H

#define NB_ 25     // blocks per recurrent gang
#define RPB_ 20    // h indices per block (25*20 = 500)
#define TPB_ 640   // threads per recurrent block = 80 cols * 8 batches

__device__ __forceinline__ float sigm(float x) { return 1.f / (1.f + expf(-x)); }
__device__ __forceinline__ float seluf(float x) {
    const float sc = 1.0507009873554805f, al = 1.6732632423543772f;
    return x > 0.f ? sc * x : sc * al * (expf(x) - 1.f);
}
// agent-scope ops: bypass L1/L2, coherent at L3; no fences / no wbl2
__device__ __forceinline__ float cohload(const float* p) {
    return __hip_atomic_load(p, __ATOMIC_RELAXED, __HIP_MEMORY_SCOPE_AGENT);
}
__device__ __forceinline__ void cohstore(float* p, float v) {
    __hip_atomic_store(p, v, __ATOMIC_RELAXED, __HIP_MEMORY_SCOPE_AGENT);
}

// ---------------- zero the flag slots ----------------
__global__ void k_zero(int* p, int n) {
    int i = blockIdx.x * blockDim.x + threadIdx.x;
    if (i < n) __hip_atomic_store(&p[i], 0, __ATOMIC_RELAXED, __HIP_MEMORY_SCOPE_AGENT);
}

// ---------------- embedding gather ----------------
__global__ __launch_bounds__(128) void k_embed(const int* __restrict__ itemv,
                                               const int* __restrict__ histi,
                                               const float* __restrict__ embW,
                                               float* __restrict__ items,
                                               float* __restrict__ histemb) {
    int row = blockIdx.x;
    int id;
    float* dst;
    if (row < 256) { id = itemv[row]; dst = items + (size_t)row * E_; }
    else           { int rr = row - 256; id = histi[rr]; dst = histemb + (size_t)rr * E_; }
    const float4* s = (const float4*)(embW + (size_t)id * E_);
    float4* d = (float4*)dst;
    if (threadIdx.x < 125) d[threadIdx.x] = s[threadIdx.x];
}

// ---------------- generic GEMM: C[M,N] = A[M,K] @ B[N,K]^T + bias[N] ----------------
#define TBM 64
#define TBN 64
#define TBK 16
__global__ __launch_bounds__(256) void k_gemm_bt(const float* __restrict__ A,
                                                 const float* __restrict__ Bm,
                                                 const float* __restrict__ bias,
                                                 float* __restrict__ C,
                                                 int M, int N, int K) {
    __shared__ float As[TBK][TBM + 1];
    __shared__ float Bs[TBK][TBN + 1];
    const int tid = threadIdx.x;
    const int tx = tid & 15, ty = tid >> 4;
    const int row0 = blockIdx.y * TBM, col0 = blockIdx.x * TBN;
    float acc[4][4] = {};
    for (int k0 = 0; k0 < K; k0 += TBK) {
#pragma unroll
        for (int i = 0; i < 4; ++i) {
            int e = tid + i * 256;
            int kk = e & 15, m = e >> 4;
            int gk = k0 + kk;
            float va = 0.f, vb = 0.f;
            int gm = row0 + m, gn = col0 + m;
            if (gk < K) {
                if (gm < M) va = A[(size_t)gm * K + gk];
                if (gn < N) vb = Bm[(size_t)gn * K + gk];
            }
            As[kk][m] = va;
            Bs[kk][m] = vb;
        }
        __syncthreads();
#pragma unroll
        for (int kk = 0; kk < TBK; ++kk) {
            float a[4], bb[4];
#pragma unroll
            for (int i = 0; i < 4; ++i) a[i] = As[kk][ty * 4 + i];
#pragma unroll
            for (int i = 0; i < 4; ++i) bb[i] = Bs[kk][tx * 4 + i];
#pragma unroll
            for (int i = 0; i < 4; ++i)
#pragma unroll
                for (int j = 0; j < 4; ++j) acc[i][j] += a[i] * bb[j];
        }
        __syncthreads();
    }
#pragma unroll
    for (int i = 0; i < 4; ++i) {
        int gm = row0 + ty * 4 + i;
        if (gm >= M) continue;
#pragma unroll
        for (int j = 0; j < 4; ++j) {
            int gn = col0 + tx * 4 + j;
            if (gn < N) C[(size_t)gm * N + gn] = acc[i][j] + (bias ? bias[gn] : 0.f);
        }
    }
}

// ---------------- multi-block batched recurrent kernel (v5) ----------------
// R3 structure (LDS-staged h) with latency cuts:
//  - staging: 7 independent uncached loads into registers, THEN LDS writes
//    (one pipelined L3 round trip instead of ~7 serialized ones)
//  - wave-parallel poll of the NB_ per-block flag slots with s_sleep backoff
//  - role-1 csg gather issued right after the poll (overlaps staging+GEMV)
__global__ __launch_bounds__(TPB_) void k_rec5(
    const float* __restrict__ xwm, const float* __restrict__ Whm,
    const float* __restrict__ xwd, const float* __restrict__ Whd,
    const int* __restrict__ dilidx,
    const float* __restrict__ xwh, const float* __restrict__ Whh,
    float* __restrict__ outm, float* __restrict__ outh,
    float* __restrict__ csg, float* __restrict__ he,
    int* __restrict__ flags) {
    __shared__ __align__(16) float h_s[8][500];
    __shared__ float z_s[80][8];
    __shared__ float c_s[RPB_][8];
    float* hflat = &h_s[0][0];
    const int tid = threadIdx.x;
    const int gb = blockIdx.x;
    const int role = gb / NB_;          // 0 main, 1 dil, 2 hist
    const int blk = gb - role * NB_;
    const int r0 = blk * RPB_;

    const float* Wh  = (role == 0) ? Whm : (role == 1) ? Whd : Whh;
    const float* xw  = (role == 0) ? xwm : (role == 1) ? xwd : xwh;
    const float* exch = (role == 0) ? outm : (role == 1) ? outh : he;
    const int nsteps = (role == 2) ? 128 : 32;
    const int rstride = (role == 2) ? 128 : S_;   // rows per batch in exch
    int* flag = flags + role * 32;      // NB_ slots used

    const int c = tid >> 3;             // 0..79
    const int b = tid & 7;
    const int gate = c / RPB_;          // 0..3 (i,f,g,o)
    const int ri = c - gate * RPB_;     // 0..19
    const int col = gate * 500 + r0 + ri;
    const float4* wp4 = (const float4*)(Wh + (size_t)col * 500);

    // staging indices (fixed per thread): i_j = tid + 640*j, j=0..6 (j=6 iff tid<160)
    const int i0 = tid,        i1 = tid + 640,  i2 = tid + 1280,
              i3 = tid + 1920, i4 = tid + 2560, i5 = tid + 3200, i6 = tid + 3840;
    const int b0 = i0 / 500, k0s = i0 - b0 * 500;
    const int b1 = i1 / 500, k1s = i1 - b1 * 500;
    const int b2 = i2 / 500, k2s = i2 - b2 * 500;
    const int b3 = i3 / 500, k3s = i3 - b3 * 500;
    const int b4 = i4 / 500, k4s = i4 - b4 * 500;
    const int b5 = i5 / 500, k5s = i5 - b5 * 500;
    const int b6 = i6 / 500, k6s = i6 - b6 * 500;  // valid iff tid<160

    if (tid < RPB_ * 8) c_s[tid >> 3][tid & 7] = 0.f;

    for (int t = 0; t < nsteps; ++t) {
        // xw load is independent of h -> issue before the poll
        float acc = xw[((size_t)(b * nsteps + t)) * G4_ + col];

        float pc_r = 0.f;   // role-1 prev cell, loaded early
        if (t > 0) {
            // ---- wait for all blocks of this gang to finish step t-1 ----
            if (tid < 64) {
                while (true) {
                    int v = (tid < NB_)
                        ? __hip_atomic_load(&flag[tid], __ATOMIC_RELAXED,
                                            __HIP_MEMORY_SCOPE_AGENT)
                        : 0x7fffffff;
                    if (__all(v >= t)) break;
                    __builtin_amdgcn_s_sleep(1);
                }
            }
            __syncthreads();

            // role-1: issue prev-cell gather now; consumed in the gate phase
            if (role == 1 && tid < RPB_ * 8) {
                int rr = tid >> 3, bb = tid & 7;
                int it = dilidx[bb * S_ + t];
                pc_r = cohload(&csg[((size_t)(bb * S_ + it)) * H_ + r0 + rr]);
            }

            // ---- batched staging: issue all loads, then write LDS ----
            // row base per staged element: role 0/2 -> row t-1; role 1 -> dilidx row
            int r_0, r_1, r_2, r_3, r_4, r_5, r_6;
            if (role == 1) {
                r_0 = dilidx[b0 * S_ + t]; r_1 = dilidx[b1 * S_ + t];
                r_2 = dilidx[b2 * S_ + t]; r_3 = dilidx[b3 * S_ + t];
                r_4 = dilidx[b4 * S_ + t]; r_5 = dilidx[b5 * S_ + t];
                r_6 = (tid < 160) ? dilidx[b6 * S_ + t] : 0;
            } else {
                r_0 = r_1 = r_2 = r_3 = r_4 = r_5 = r_6 = t - 1;
            }
            float v0 = cohload(&exch[((size_t)(b0 * rstride + r_0)) * H_ + k0s]);
            float v1 = cohload(&exch[((size_t)(b1 * rstride + r_1)) * H_ + k1s]);
            float v2 = cohload(&exch[((size_t)(b2 * rstride + r_2)) * H_ + k2s]);
            float v3 = cohload(&exch[((size_t)(b3 * rstride + r_3)) * H_ + k3s]);
            float v4 = cohload(&exch[((size_t)(b4 * rstride + r_4)) * H_ + k4s]);
            float v5 = cohload(&exch[((size_t)(b5 * rstride + r_5)) * H_ + k5s]);
            float v6 = (tid < 160)
                ? cohload(&exch[((size_t)(b6 * rstride + r_6)) * H_ + k6s]) : 0.f;
            hflat[i0] = v0; hflat[i1] = v1; hflat[i2] = v2;
            hflat[i3] = v3; hflat[i4] = v4; hflat[i5] = v5;
            if (tid < 160) hflat[i6] = v6;
            __syncthreads();

            // ---- z += h @ Wh^T (this block's 80 columns, 8 batches) ----
            const float4* hp4 = (const float4*)&h_s[b][0];
            float s0 = 0.f, s1 = 0.f, s2 = 0.f, s3 = 0.f;
#pragma unroll 4
            for (int k4 = 0; k4 < 124; k4 += 4) {
                float4 w0 = wp4[k4],     h0 = hp4[k4];
                float4 w1 = wp4[k4 + 1], h1 = hp4[k4 + 1];
                float4 w2 = wp4[k4 + 2], h2 = hp4[k4 + 2];
                float4 w3 = wp4[k4 + 3], h3 = hp4[k4 + 3];
                s0 += w0.x * h0.x + w0.y * h0.y + w0.z * h0.z + w0.w * h0.w;
                s1 += w1.x * h1.x + w1.y * h1.y + w1.z * h1.z + w1.w * h1.w;
                s2 += w2.x * h2.x + w2.y * h2.y + w2.z * h2.z + w2.w * h2.w;
                s3 += w3.x * h3.x + w3.y * h3.y + w3.z * h3.z + w3.w * h3.w;
            }
            float4 wt = wp4[124], ht = hp4[124];
            s0 += wt.x * ht.x + wt.y * ht.y + wt.z * ht.z + wt.w * ht.w;
            acc += (s0 + s1) + (s2 + s3);
        }
        z_s[c][b] = acc;
        __syncthreads();

        // ---- gate update for this block's 20 h-indices ----
        if (tid < RPB_ * 8) {
            int rr = tid >> 3, bb = tid & 7;
            float zi = z_s[rr][bb];
            float zf = z_s[RPB_ + rr][bb];
            float zg = z_s[2 * RPB_ + rr][bb];
            float zo = z_s[3 * RPB_ + rr][bb];
            int r = r0 + rr;
            float pc = (role == 1) ? pc_r : c_s[rr][bb];
            float cc = sigm(zf) * pc + sigm(zi) * tanhf(zg);
            float hh = sigm(zo) * tanhf(cc);
            if (role == 0) {
                c_s[rr][bb] = cc;
                cohstore(&outm[((size_t)(bb * S_ + t)) * H_ + r], hh);
            } else if (role == 2) {
                c_s[rr][bb] = cc;
                cohstore(&he[((size_t)(bb * 128 + t)) * H_ + r], hh);
            } else {
                cohstore(&outh[((size_t)(bb * S_ + t)) * H_ + r], hh);
                cohstore(&csg[((size_t)(bb * S_ + t)) * H_ + r], cc);
            }
        }
        __syncthreads();   // drains vmcnt(0): agent-scope stores complete at L3
        if (tid == 0)
            __hip_atomic_store(&flag[blk], t + 1, __ATOMIC_RELAXED,
                               __HIP_MEMORY_SCOPE_AGENT);
    }
}

// ---------------- masked mean pooling ----------------
__global__ __launch_bounds__(512) void k_pool(const float* __restrict__ outm,
                                              const float* __restrict__ mask,
                                              float* __restrict__ pooled) {
    int b = blockIdx.x, tid = threadIdx.x;
    if (tid >= 500) return;
    float acc = 0.f, den = 0.f;
    for (int s = 0; s < S_; ++s) {
        float mk = mask[b * S_ + s];
        acc += outm[((size_t)(b * S_ + s)) * H_ + tid] * mk;
        den += mk;
    }
    pooled[b * H_ + tid] = acc / den;
}

// ---------------- session rep: sess[b,j,s,:] and avgd[b,j,s] ----------------
__global__ __launch_bounds__(512) void k_sess(const int* __restrict__ seqtim,
                                              const int* __restrict__ itemv,
                                              const int* __restrict__ histt,
                                              const int* __restrict__ histi,
                                              const float* __restrict__ timsim,
                                              const float* __restrict__ poid,
                                              const float* __restrict__ he,
                                              float* __restrict__ sess,
                                              float* __restrict__ avgd) {
    int bi = blockIdx.x;                // B*J*31
    int s = bi % 31;
    int tmpv = bi / 31;
    int j = tmpv & 3, b = tmpv >> 2;
    __shared__ float w[L_];
    __shared__ float pd[L_];
    __shared__ float stats[1];
    int tid = threadIdx.x;
    int st = seqtim[b * S_ + s];
    if (tid < L_) {
        int ht = histt[(b * J_ + j) * L_ + tid];
        w[tid] = timsim[st * NT_ + ht];
    }
    if (tid >= 64 && tid < 64 + L_) {   // parallel poi_dist gather
        int l = tid - 64;
        int iv = itemv[b * S_ + s];
        pd[l] = poid[(size_t)iv * NI_ + histi[(b * J_ + j) * L_ + l]];
    }
    __syncthreads();
    if (tid == 64) {
        float a = 0.f;
        for (int l = 0; l < L_; ++l) a += pd[l];
        avgd[(b * J_ + j) * 31 + s] = a * (1.f / 32.f);
    }
    if (tid == 0) {
        float m = -1e30f;
        for (int l = 0; l < L_; ++l) m = fmaxf(m, w[l]);
        float sm = 0.f;
        for (int l = 0; l < L_; ++l) { float e = expf(w[l] - m); w[l] = e; sm += e; }
        stats[0] = 1.f / sm;
    }
    __syncthreads();
    if (tid < 500) {
        float inv = stats[0];
        float acc = 0.f;
        const float* hp = he + ((size_t)(b * J_ * L_ + j * L_)) * H_ + tid;
        for (int l = 0; l < L_; ++l) acc += w[l] * inv * hp[(size_t)l * H_];
        sess[((size_t)((b * J_ + j) * 31 + s)) * H_ + tid] = acc;
    }
}

// ---------------- attention 1 ----------------
__global__ __launch_bounds__(512) void k_att1(const float* __restrict__ sess,
                                              const float* __restrict__ pooled,
                                              float* __restrict__ att1) {
    int bi = blockIdx.x;   // B*31
    int s = bi % 31, b = bi / 31;
    __shared__ float vec[H_];
    __shared__ float part[512];
    int tid = threadIdx.x;
    if (tid < 500) vec[tid] = pooled[b * H_ + tid];
    __syncthreads();
    int j = tid >> 7, i = tid & 127;
    const float* sp = sess + ((size_t)((b * J_ + j) * 31 + s)) * H_;
    float acc = 0.f;
    for (int h = i; h < H_; h += 128) acc += sp[h] * vec[h];
    part[tid] = acc;
    __syncthreads();
    for (int off = 64; off > 0; off >>= 1) {
        if (i < off) part[tid] += part[tid + off];
        __syncthreads();
    }
    float d0 = part[0], d1 = part[128], d2 = part[256], d3 = part[384];
    float m = fmaxf(fmaxf(d0, d1), fmaxf(d2, d3));
    float e0 = expf(d0 - m), e1 = expf(d1 - m), e2 = expf(d2 - m), e3 = expf(d3 - m);
    float inv = 1.f / (e0 + e1 + e2 + e3);
    if (tid < 500) {
        const float* s0 = sess + ((size_t)(b * J_ * 31 + s)) * H_ + tid;
        const size_t js = (size_t)31 * H_;
        float r = e0 * inv * s0[0] + e1 * inv * s0[js] + e2 * inv * s0[2 * js] + e3 * inv * s0[3 * js];
        att1[((size_t)(b * 31 + s)) * H_ + tid] = r;
    }
}

// ---------------- attention 2 ----------------
__global__ __launch_bounds__(512) void k_att2(const float* __restrict__ sess,
                                              const float* __restrict__ outy,
                                              const float* __restrict__ outm,
                                              const float* __restrict__ avgd,
                                              float* __restrict__ X) {
    int bi = blockIdx.x;   // B*31
    int s = bi % 31, b = bi / 31;
    __shared__ float vec[H_];
    __shared__ float part[512];
    int tid = threadIdx.x;
    if (tid < 500)
        vec[tid] = 0.5f * seluf(outy[((size_t)(b * 31 + s)) * H_ + tid]) +
                   0.5f * outm[((size_t)(b * S_ + s)) * H_ + tid];
    __syncthreads();
    int j = tid >> 7, i = tid & 127;
    const float* sp = sess + ((size_t)((b * J_ + j) * 31 + s)) * H_;
    float acc = 0.f;
    for (int h = i; h < H_; h += 128) acc += sp[h] * vec[h];
    part[tid] = acc;
    __syncthreads();
    for (int off = 64; off > 0; off >>= 1) {
        if (i < off) part[tid] += part[tid + off];
        __syncthreads();
    }
    float d0 = part[0]   / avgd[(b * J_ + 0) * 31 + s];
    float d1 = part[128] / avgd[(b * J_ + 1) * 31 + s];
    float d2 = part[256] / avgd[(b * J_ + 2) * 31 + s];
    float d3 = part[384] / avgd[(b * J_ + 3) * 31 + s];
    float m = fmaxf(fmaxf(d0, d1), fmaxf(d2, d3));
    float e0 = expf(d0 - m), e1 = expf(d1 - m), e2 = expf(d2 - m), e3 = expf(d3 - m);
    float inv = 1.f / (e0 + e1 + e2 + e3);
    if (tid < 500) {
        const float* s0 = sess + ((size_t)(b * J_ * 31 + s)) * H_ + tid;
        const size_t js = (size_t)31 * H_;
        float r = e0 * inv * s0[0] + e1 * inv * s0[js] + e2 * inv * s0[2 * js] + e3 * inv * s0[3 * js];
        X[((size_t)(b * S_ + s)) * 1000 + tid] = seluf(r);
    }
}

// ---------------- mix ----------------
__global__ __launch_bounds__(512) void k_mix(const float* __restrict__ outm,
                                             const float* __restrict__ outh,
                                             float* __restrict__ X) {
    int bs = blockIdx.x;   // B*S
    int tid = threadIdx.x;
    if (tid >= 500) return;
    size_t idx = (size_t)bs * H_ + tid;
    float om = 0.5f * (seluf(outm[idx]) + seluf(outh[idx]));
    X[(size_t)bs * 1000 + 500 + tid] = om;
    if ((bs & (S_ - 1)) == S_ - 1) X[(size_t)bs * 1000 + tid] = 0.f;
}

// ---------------- in-place log_softmax over rows of 5000 ----------------
__global__ __launch_bounds__(512) void k_lsm(float* __restrict__ out) {
    int row = blockIdx.x, tid = threadIdx.x;
    float* p = out + (size_t)row * NI_;
    __shared__ float red[512];
    float m = -1e30f;
    for (int i = tid; i < NI_; i += 512) m = fmaxf(m, p[i]);
    red[tid] = m;
    __syncthreads();
    for (int off = 256; off > 0; off >>= 1) {
        if (tid < off) red[tid] = fmaxf(red[tid], red[tid + off]);
        __syncthreads();
    }
    m = red[0];
    __syncthreads();
    float sm = 0.f;
    for (int i = tid; i < NI_; i += 512) sm += expf(p[i] - m);
    red[tid] = sm;
    __syncthreads();
    for (int off = 256; off > 0; off >>= 1) {
        if (tid < off) red[tid] += red[tid + off];
        __syncthreads();
    }
    float lse = m + logf(red[0]);
    __syncthreads();
    for (int i = tid; i < NI_; i += 512) p[i] -= lse;
}

extern "C" void kernel_launch(void* const* d_in, const int* in_sizes, int n_in,
                              void* d_out, int out_size, void* d_ws, size_t ws_size,
                              hipStream_t stream) {
    const int* item_vectors = (const int*)d_in[0];
    const int* sequence_tim = (const int*)d_in[1];
    const int* dilated_idx  = (const int*)d_in[2];
    const int* hist_items   = (const int*)d_in[3];
    const int* hist_tims    = (const int*)d_in[4];
    const float* mask       = (const float*)d_in[5];
    const float* tim_sim    = (const float*)d_in[6];
    const float* poi_dist   = (const float*)d_in[7];
    const float* emb_W      = (const float*)d_in[8];
    const float* lstm_Wi    = (const float*)d_in[9];
    const float* lstm_Wh    = (const float*)d_in[10];
    const float* lstm_b     = (const float*)d_in[11];
    const float* hist_Wi    = (const float*)d_in[12];
    const float* hist_Wh    = (const float*)d_in[13];
    const float* hist_b     = (const float*)d_in[14];
    const float* dil_Wi     = (const float*)d_in[15];
    const float* dil_Wh     = (const float*)d_in[16];
    const float* dil_b      = (const float*)d_in[17];
    const float* lin1_W     = (const float*)d_in[18];
    const float* lin1_b     = (const float*)d_in[19];
    const float* lin_W      = (const float*)d_in[20];
    const float* lin_b      = (const float*)d_in[21];
    float* out = (float*)d_out;
    float* ws  = (float*)d_ws;

    // workspace layout (float offsets)
    float* items   = ws + 0;        // 128000
    float* histemb = ws + 128000;   // 512000
    float* xwm     = ws + 640000;   // 512000
    float* xwd     = ws + 1152000;  // 512000
    float* xwh     = ws + 1664000;  // 2048000
    float* outm    = ws + 3712000;  // 128000
    float* outh    = ws + 3840000;  // 128000
    float* csg     = ws + 3968000;  // 128000
    float* he      = ws + 4096000;  // 512000
    float* pooled  = ws + 4608000;  // 4000
    float* sess    = ws + 4612000;  // 496000
    float* avgd    = ws + 5108000;  // 992
    float* att1    = ws + 5108992;  // 124000
    float* outy    = ws + 5232992;  // 124000
    float* Xbuf    = ws + 5356992;  // 256000
    int*   flags   = (int*)(ws + 5612992);  // 3*32 ints

    k_zero<<<dim3(1), dim3(128), 0, stream>>>(flags, 96);
    k_embed<<<dim3(1280), dim3(128), 0, stream>>>(item_vectors, hist_items, emb_W, items, histemb);

    // input-side GEMMs with bias folded in
    k_gemm_bt<<<dim3(32, 4), dim3(256), 0, stream>>>(items, lstm_Wi, lstm_b, xwm, 256, G4_, E_);
    k_gemm_bt<<<dim3(32, 4), dim3(256), 0, stream>>>(items, dil_Wi, dil_b, xwd, 256, G4_, E_);
    k_gemm_bt<<<dim3(32, 16), dim3(256), 0, stream>>>(histemb, hist_Wi, hist_b, xwh, 1024, G4_, E_);

    k_rec5<<<dim3(3 * NB_), dim3(TPB_), 0, stream>>>(
        xwm, lstm_Wh, xwd, dil_Wh, dilated_idx, xwh, hist_Wh,
        outm, outh, csg, he, flags);

    k_pool<<<dim3(B_), dim3(512), 0, stream>>>(outm, mask, pooled);
    k_sess<<<dim3(B_ * J_ * 31), dim3(512), 0, stream>>>(sequence_tim, item_vectors, hist_tims,
                                                         hist_items, tim_sim, poi_dist, he, sess, avgd);
    k_att1<<<dim3(B_ * 31), dim3(512), 0, stream>>>(sess, pooled, att1);
    k_gemm_bt<<<dim3(8, 4), dim3(256), 0, stream>>>(att1, lin1_W, lin1_b, outy, 248, H_, H_);
    k_att2<<<dim3(B_ * 31), dim3(512), 0, stream>>>(sess, outy, outm, avgd, Xbuf);
    k_mix<<<dim3(B_ * S_), dim3(512), 0, stream>>>(outm, outh, Xbuf);

    k_gemm_bt<<<dim3(79, 4), dim3(256), 0, stream>>>(Xbuf, lin_W, lin_b, out, 256, NI_, 1000);
    k_lsm<<<dim3(256), dim3(512), 0, stream>>>(out);
}